// Round 15
// baseline (1981.497 us; speedup 1.0000x reference)
//
#include <hip/hip_runtime.h>
#include <cmath>

// B=32, T=128, E=512, H=1024, 4H=4096
typedef __attribute__((ext_vector_type(8))) short short8;
typedef __attribute__((ext_vector_type(4))) float f32x4;
typedef unsigned long long u64;

__device__ inline short bf16r(float x) {
  union { float f; unsigned u; } v; v.f = x;
  unsigned r = (v.u + 0x7fff + ((v.u >> 16) & 1)) >> 16;
  return (short)r;
}
__device__ inline float bf2f(short s) {
  union { unsigned u; float f; } v; v.u = ((unsigned)(unsigned short)s) << 16;
  return v.f;
}

// hx layout: [t][chunk c=u>>4][b(32)][u&15] bf16 ; 129 buffers of 32768 shorts.
// ---------- small prep kernels ----------
__global__ __launch_bounds__(256) void init2(const float* __restrict__ h0,
                                             const float* __restrict__ c0,
                                             short* __restrict__ hx0,
                                             float* __restrict__ c) {
  int idx = blockIdx.x * 256 + threadIdx.x;  // (b,u) row-major
  int b = idx >> 10, u = idx & 1023;
  hx0[(u >> 4) * 512 + b * 16 + (u & 15)] = bf16r(h0[idx]);
  c[idx] = c0[idx];
}

__global__ __launch_bounds__(256) void finalize2(const short* __restrict__ hxf,
                                                 const float* __restrict__ c,
                                                 float* __restrict__ out) {
  int idx = blockIdx.x * 256 + threadIdx.x;  // (b,u)
  int b = idx >> 10, u = idx & 1023;
  out[idx] = bf2f(hxf[(u >> 4) * 512 + b * 16 + (u & 15)]);
  out[32768 + idx] = c[idx];
}

__global__ __launch_bounds__(256) void zero_cnt(unsigned* __restrict__ c) {
  c[blockIdx.x * 256 + threadIdx.x] = 0u;  // 16 blocks -> 4096 u32
}

// x (B,T,E) fp32 -> xb rows r=t*32+b, (4096,512) bf16 ; 8 elems/thread
__global__ __launch_bounds__(256) void cast_x(const float* __restrict__ x,
                                              short* __restrict__ xb) {
  int v = blockIdx.x * 256 + threadIdx.x;  // 0..262143 (vector index)
  int e8 = v & 63, t = (v >> 6) & 127, b = v >> 13;
  const float* src = x + (((size_t)b * 128 + t) << 9) + e8 * 8;
  float4 f0 = *(const float4*)src;
  float4 f1 = *(const float4*)(src + 4);
  short8 o;
  o[0] = bf16r(f0.x); o[1] = bf16r(f0.y); o[2] = bf16r(f0.z); o[3] = bf16r(f0.w);
  o[4] = bf16r(f1.x); o[5] = bf16r(f1.y); o[6] = bf16r(f1.z); o[7] = bf16r(f1.w);
  *(short8*)(xb + ((((t << 5) + b) << 9) + e8 * 8)) = o;
}

// permuted biases: bp[l][n'] = b_l[(n'&3)*1024 + (n'>>2)]
__global__ __launch_bounds__(256) void bias_perm(const float* __restrict__ b1,
                                                 const float* __restrict__ b2,
                                                 const float* __restrict__ b3,
                                                 const float* __restrict__ b4,
                                                 float* __restrict__ bp) {
  int idx = blockIdx.x * 256 + threadIdx.x;  // 0..16383
  int l = idx >> 12, c = idx & 4095;
  const float* s = (l == 0) ? b1 : (l == 1) ? b2 : (l == 2) ? b3 : b4;
  bp[idx] = s[((c & 3) << 10) | (c >> 2)];
}

// in fp32 (R,C) -> out bf16 (C,R); GPERM: out-row n' = (c&1023)*4 + (c>>10)
template <bool GPERM>
__global__ __launch_bounds__(256) void transpose_cast(const float* __restrict__ in,
                                                      short* __restrict__ out,
                                                      int R, int C) {
  __shared__ float tile[32][33];
  int c0 = blockIdx.x * 32, r0 = blockIdx.y * 32;
  int x = threadIdx.x & 31, y = threadIdx.x >> 5;
#pragma unroll
  for (int i = 0; i < 4; ++i)
    tile[y + i * 8][x] = in[(size_t)(r0 + y + i * 8) * C + c0 + x];
  __syncthreads();
#pragma unroll
  for (int i = 0; i < 4; ++i) {
    int c = c0 + y + i * 8;
    int n = GPERM ? (((c & 1023) << 2) | (c >> 10)) : c;
    out[(size_t)n * R + r0 + x] = bf16r(tile[x][y + i * 8]);
  }
}

// ---------- bf16 MFMA GEMM (standalone; used for layer-0 xW and final out) ----
template <int MODE, bool AHX>
__global__ __launch_bounds__(256) void gemm_bf16(const short* __restrict__ A,
                                                 const short* __restrict__ Bt,
                                                 const float* __restrict__ bias,
                                                 void* __restrict__ Cout,
                                                 int M, int N, int K) {
  __shared__ short As[128 * 40];
  __shared__ short Bs[128 * 40];
  const int tid = threadIdx.x;
  const int lane = tid & 63, wave = tid >> 6;
  const int lrow = lane & 15, lk = lane >> 4;
  const int m0 = (wave >> 1) * 64, n0 = (wave & 1) * 64;
  const int r = tid & 127, half = tid >> 7;
  const int mbase = blockIdx.y * 128, nbase = blockIdx.x * 128;

  f32x4 acc[4][4] = {};

  const short* Ab = A + (size_t)(mbase + r) * K + half * 16;
  const short* Ahx =
      A + (size_t)((mbase + r) >> 5) * 32768 + half * 512 + ((mbase + r) & 31) * 16;
  const short* Bb = Bt + (size_t)(nbase + r) * K + half * 16;
  short* AsW = As + r * 40 + half * 16;
  short* BsW = Bs + r * 40 + half * 16;

  for (int k0 = 0; k0 < K; k0 += 32) {
    short8 av0, av1;
    if constexpr (AHX) {
      const short* ap = Ahx + (k0 >> 4) * 512;
      av0 = *(const short8*)ap;
      av1 = *(const short8*)(ap + 8);
    } else {
      av0 = *(const short8*)(Ab + k0);
      av1 = *(const short8*)(Ab + k0 + 8);
    }
    short8 bv0 = *(const short8*)(Bb + k0);
    short8 bv1 = *(const short8*)(Bb + k0 + 8);
    __syncthreads();
    *(short8*)(AsW) = av0;
    *(short8*)(AsW + 8) = av1;
    *(short8*)(BsW) = bv0;
    *(short8*)(BsW + 8) = bv1;
    __syncthreads();
    short8 af[4], bfr[4];
#pragma unroll
    for (int i = 0; i < 4; ++i)
      af[i] = *(const short8*)(As + (m0 + i * 16 + lrow) * 40 + lk * 8);
#pragma unroll
    for (int i = 0; i < 4; ++i)
      bfr[i] = *(const short8*)(Bs + (n0 + i * 16 + lrow) * 40 + lk * 8);
#pragma unroll
    for (int i = 0; i < 4; ++i)
#pragma unroll
      for (int j = 0; j < 4; ++j)
        acc[i][j] = __builtin_amdgcn_mfma_f32_16x16x32_bf16(af[i], bfr[j],
                                                            acc[i][j], 0, 0, 0);
  }

#pragma unroll
  for (int i = 0; i < 4; ++i) {
    const int grow0 = mbase + m0 + i * 16 + lk * 4;
#pragma unroll
    for (int j = 0; j < 4; ++j) {
      const int gcol = nbase + n0 + j * 16 + lrow;
      const float bv = bias[gcol];
      f32x4 v = acc[i][j];
      if constexpr (MODE == 1) {
        float* o = (float*)Cout;
#pragma unroll
        for (int jj = 0; jj < 4; ++jj)
          o[(size_t)(grow0 + jj) * N + gcol] = v[jj] + bv;
      } else if constexpr (MODE == 2) {
        short* o = (short*)Cout;
#pragma unroll
        for (int jj = 0; jj < 4; ++jj)
          o[(size_t)(grow0 + jj) * N + gcol] = bf16r(fmaxf(v[jj] + bv, 0.f));
      } else {
        float* o = (float*)Cout;
#pragma unroll
        for (int jj = 0; jj < 4; ++jj) {
          int rr = grow0 + jj;
          int orow = ((rr & 31) << 7) | (rr >> 5);
          o[(size_t)orow * N + gcol] = v[jj] + bv;
        }
      }
    }
  }
}

// ---------- persistent recurrent kernel (whole layer, 128 steps) ----------
// Grid = 256 blocks (1 block/CU). Blocks 0..63: recurrence (R8/R12 protocol,
// flag every step; t==127 dual-stores final h to hx[0]). Blocks 64..127:
// transpose helpers. Blocks 128..255: GEMM helpers (next layer's xW / dense
// D1), tile-gated on producer flags with LONG-SLEEP polling (s_sleep(32)) so
// 8k helper lanes don't contend with producers' latency-critical flag stores;
// xWp written with non-temporal stores to avoid L2 thrash.
#define PBLK 64
__global__ __launch_bounds__(256) void lstm_persist(
    const float* xWp, const short* __restrict__ Utp, short* __restrict__ hx,
    float* __restrict__ cst, unsigned* __restrict__ arr, int ebase,
    const float* __restrict__ tA, short* __restrict__ oA, int CA, int gpA,
    const float* __restrict__ tB, short* __restrict__ oB, int CB, int gpB,
    const short* __restrict__ gBt, const float* __restrict__ gBias, void* gOut,
    int gLg, int gMode) {
  __shared__ short Hs[32768];  // 64KB: h_t chunks (compute) / As+Bs (gemm help)
  __shared__ float tile[32][33];
  const int tid = threadIdx.x;
  const int bid = blockIdx.x;

  if (bid >= 128) {  // ---- GEMM helper: next layer's xW (or dense D1) ----
    const int hid = bid - 128;  // 0..127
    const int lane = tid & 63, wave = tid >> 6;
    const int lrow = lane & 15, lk = lane >> 4;
    const int m0 = (wave >> 1) * 64, n0 = (wave & 1) * 64;
    const int r = tid & 127, half = tid >> 7;
    const short* hxseq = hx + 32768;
    short* As = Hs;
    short* Bs = Hs + 5120;
    const int ntiles = 32 << gLg;
    int lastby = -1;
    for (int ti = hid; ti < ntiles; ti += 128) {
      const int by = ti >> gLg, bx = ti - (by << gLg);
      if (by != lastby) {
        lastby = by;
        const unsigned tgt = (unsigned)(ebase + 4 * by + 4);
        if (tid < PBLK)
          while (__hip_atomic_load(arr + (tid << 6), __ATOMIC_RELAXED,
                                   __HIP_MEMORY_SCOPE_AGENT) < tgt)
            __builtin_amdgcn_s_sleep(32);  // helpers have ~14us slack: poll
                                           // rarely, don't contend flag lines
        __syncthreads();
      }
      const int mbase = by * 128, nbase = bx * 128;
      f32x4 acc[4][4] = {};
      const short* Ahx = hxseq + (size_t)((mbase + r) >> 5) * 32768 +
                         half * 512 + ((mbase + r) & 31) * 16;
      const short* Bb = gBt + (size_t)(nbase + r) * 1024 + half * 16;
      short* AsW = As + r * 40 + half * 16;
      short* BsW = Bs + r * 40 + half * 16;
      for (int k0 = 0; k0 < 1024; k0 += 32) {
        const short* ap = Ahx + (k0 >> 4) * 512;
        short8 av0 = *(const short8*)ap;
        short8 av1 = *(const short8*)(ap + 8);
        short8 bv0 = *(const short8*)(Bb + k0);
        short8 bv1 = *(const short8*)(Bb + k0 + 8);
        __syncthreads();
        *(short8*)(AsW) = av0;
        *(short8*)(AsW + 8) = av1;
        *(short8*)(BsW) = bv0;
        *(short8*)(BsW + 8) = bv1;
        __syncthreads();
        short8 af[4], bfr[4];
#pragma unroll
        for (int i = 0; i < 4; ++i)
          af[i] = *(const short8*)(As + (m0 + i * 16 + lrow) * 40 + lk * 8);
#pragma unroll
        for (int i = 0; i < 4; ++i)
          bfr[i] = *(const short8*)(Bs + (n0 + i * 16 + lrow) * 40 + lk * 8);
#pragma unroll
        for (int i = 0; i < 4; ++i)
#pragma unroll
          for (int j = 0; j < 4; ++j)
            acc[i][j] = __builtin_amdgcn_mfma_f32_16x16x32_bf16(
                af[i], bfr[j], acc[i][j], 0, 0, 0);
      }
#pragma unroll
      for (int i = 0; i < 4; ++i) {
        const int grow0 = mbase + m0 + i * 16 + lk * 4;
#pragma unroll
        for (int j = 0; j < 4; ++j) {
          const int gcol = nbase + n0 + j * 16 + lrow;
          const float bv = gBias[gcol];
          f32x4 v = acc[i][j];
          if (gMode == 1) {
            float* o = (float*)gOut;
#pragma unroll
            for (int jj = 0; jj < 4; ++jj)
              __builtin_nontemporal_store(
                  v[jj] + bv, &o[(size_t)(grow0 + jj) * 4096 + gcol]);
          } else {
            short* o = (short*)gOut;
#pragma unroll
            for (int jj = 0; jj < 4; ++jj)
              o[(size_t)(grow0 + jj) * 1024 + gcol] =
                  bf16r(fmaxf(v[jj] + bv, 0.f));
          }
        }
      }
      __syncthreads();  // WAR before next tile's staging writes
    }
    return;
  }

  if (bid >= PBLK) {  // ---- transpose helper: next stage's weights ----
    const int hid = bid - PBLK;
    const int x = tid & 31, y = tid >> 5;
    for (int job = 0; job < 2; ++job) {
      const float* in = job ? tB : tA;
      short* out = job ? oB : oA;
      const int C = job ? CB : CA;
      const int gp = job ? gpB : gpA;
      const int ctiles = C >> 5;
      for (int ti = hid; ti < C; ti += 64) {
        const int cx = ti % ctiles, ry = ti / ctiles;
        __syncthreads();
#pragma unroll
        for (int i = 0; i < 4; ++i)
          tile[y + i * 8][x] = in[(size_t)(ry * 32 + y + i * 8) * C + cx * 32 + x];
        __syncthreads();
#pragma unroll
        for (int i = 0; i < 4; ++i) {
          int c = cx * 32 + y + i * 8;
          int n = gp ? (((c & 1023) << 2) | (c >> 10)) : c;
          out[(size_t)n * 1024 + ry * 32 + x] = bf16r(tile[x][y + i * 8]);
        }
      }
    }
    return;
  }

  // ---- recurrence block (R8/R12 protocol) ----
  const int lane = tid & 63, wave = tid >> 6;
  const int lrow = lane & 15, lk = lane >> 4;
  const int ucol = bid * 64 + wave * 16 + lrow;    // A-operand row (U col)
  const int col4 = bid * 64 + wave * 16 + lk * 4;  // first z-col of this lane
  const int u = bid * 16 + wave * 4 + lk;          // unit owned by this lane

  short8 ureg[32];
  {
    const short* Ub = Utp + (size_t)ucol * 1024 + lk * 8;
#pragma unroll
    for (int j = 0; j < 32; ++j) ureg[j] = *(const short8*)(Ub + j * 32);
  }

  float creg0 = cst[lrow * 1024 + u];
  float creg1 = cst[(lrow + 16) * 1024 + u];

  f32x4 cur0 = *(const f32x4*)(xWp + (size_t)lrow * 4096 + col4);
  f32x4 cur1 = *(const f32x4*)(xWp + (size_t)(lrow + 16) * 4096 + col4);

  for (int t = 0; t < 128; ++t) {
    const unsigned ep = (unsigned)(ebase + t);
    const char* src = (const char*)(hx + (size_t)t * 32768) + tid * 16;
    char* dst = (char*)Hs + tid * 16;

    if (t) {
      if (tid < 32)
        while (__hip_atomic_load(arr + (tid << 6), __ATOMIC_RELAXED,
                                 __HIP_MEMORY_SCOPE_AGENT) < ep)
          __builtin_amdgcn_s_sleep(1);
      __syncthreads();  // WAR on Hs + poll half 1
    }
#pragma unroll
    for (int i = 0; i < 8; ++i)
      __builtin_amdgcn_global_load_lds(
          (const __attribute__((address_space(1))) void*)(src + i * 4096),
          (__attribute__((address_space(3))) void*)(dst + i * 4096), 16, 0, 0);
    if (t) {
      if (tid < 32)
        while (__hip_atomic_load(arr + ((32 + tid) << 6), __ATOMIC_RELAXED,
                                 __HIP_MEMORY_SCOPE_AGENT) < ep)
          __builtin_amdgcn_s_sleep(1);
      __syncthreads();
    }
#pragma unroll
    for (int i = 8; i < 16; ++i)
      __builtin_amdgcn_global_load_lds(
          (const __attribute__((address_space(1))) void*)(src + i * 4096),
          (__attribute__((address_space(3))) void*)(dst + i * 4096), 16, 0, 0);
    __syncthreads();  // staging complete

    f32x4 acc0 = cur0, acc1 = cur1;

    // prefetch next step's xW (completes during MFMA/gates)
    if (t < 127) {
      const float* xb = xWp + (size_t)(t + 1) * 32 * 4096 + col4;
      cur0 = *(const f32x4*)(xb + (size_t)lrow * 4096);
      cur1 = *(const f32x4*)(xb + (size_t)(lrow + 16) * 4096);
    }

    // MFMA (swapped): acc = U-frag x h-frag
    const char* HsB = (const char*)Hs;
#pragma unroll
    for (int j = 0; j < 32; ++j) {
      int c0 = (2 * j + (lk >> 1)) * 1024 + lrow * 32 + (lk & 1) * 16;
      short8 b0 = *(const short8*)(HsB + c0);
      short8 b1 = *(const short8*)(HsB + c0 + 512);
      acc0 = __builtin_amdgcn_mfma_f32_16x16x32_bf16(ureg[j], b0, acc0, 0, 0, 0);
      acc1 = __builtin_amdgcn_mfma_f32_16x16x32_bf16(ureg[j], b1, acc1, 0, 0, 0);
    }

    // gates: all 4 in-lane (gate = reg index)
    int p0, p1;
    {
      float gi = 1.f / (1.f + __expf(-acc0[0]));
      float gf = 1.f / (1.f + __expf(-acc0[1]));
      float gg = fmaxf(acc0[2], 0.f);
      float go = 1.f / (1.f + __expf(-acc0[3]));
      float cn = gf * creg0 + gi * gg;
      creg0 = cn;
      p0 = (int)(unsigned short)bf16r(go * fmaxf(cn, 0.f));
    }
    {
      float gi = 1.f / (1.f + __expf(-acc1[0]));
      float gf = 1.f / (1.f + __expf(-acc1[1]));
      float gg = fmaxf(acc1[2], 0.f);
      float go = 1.f / (1.f + __expf(-acc1[3]));
      float cn = gf * creg1 + gi * gg;
      creg1 = cn;
      p1 = (int)(unsigned short)bf16r(go * fmaxf(cn, 0.f));
    }

    // pack: u64 = 4 units (lk 0..3) of this wave for one b; 8 shfl total
    {
      int a0 = __shfl(p0, lrow, 64);
      int a1 = __shfl(p0, lrow + 16, 64);
      int a2 = __shfl(p0, lrow + 32, 64);
      int a3 = __shfl(p0, lrow + 48, 64);
      int b0 = __shfl(p1, lrow, 64);
      int b1 = __shfl(p1, lrow + 16, 64);
      int b2 = __shfl(p1, lrow + 32, 64);
      int b3 = __shfl(p1, lrow + 48, 64);
      if (lk == 0) {
        short* hnx = hx + (size_t)(t + 1) * 32768 + bid * 512 + wave * 4;
        u64 pk0 = (u64)(unsigned)((a0 & 0xffff) | (a1 << 16)) |
                  ((u64)(unsigned)((a2 & 0xffff) | (a3 << 16)) << 32);
        u64 pk1 = (u64)(unsigned)((b0 & 0xffff) | (b1 << 16)) |
                  ((u64)(unsigned)((b2 & 0xffff) | (b3 << 16)) << 32);
        __hip_atomic_store((u64*)(hnx + lrow * 16), pk0, __ATOMIC_RELAXED,
                           __HIP_MEMORY_SCOPE_AGENT);
        __hip_atomic_store((u64*)(hnx + (lrow + 16) * 16), pk1, __ATOMIC_RELAXED,
                           __HIP_MEMORY_SCOPE_AGENT);
        if (t == 127) {  // final h -> hx[0] (replaces copy_h; same values)
          short* hz = hx + bid * 512 + wave * 4;
          __hip_atomic_store((u64*)(hz + lrow * 16), pk0, __ATOMIC_RELAXED,
                             __HIP_MEMORY_SCOPE_AGENT);
          __hip_atomic_store((u64*)(hz + (lrow + 16) * 16), pk1,
                             __ATOMIC_RELAXED, __HIP_MEMORY_SCOPE_AGENT);
        }
      }
    }

    // drain + flag EVERY step (incl. t==127 so helpers can gate on h[127])
    __syncthreads();
    if (tid == 0)
      __hip_atomic_store(arr + (bid << 6), (unsigned)(ebase + t + 1),
                         __ATOMIC_RELAXED, __HIP_MEMORY_SCOPE_AGENT);
  }

  cst[lrow * 1024 + u] = creg0;
  cst[(lrow + 16) * 1024 + u] = creg1;
}

// ---------- launch ----------
extern "C" void kernel_launch(void* const* d_in, const int* in_sizes, int n_in,
                              void* d_out, int out_size, void* d_ws, size_t ws_size,
                              hipStream_t stream) {
  const float* x = (const float*)d_in[0];
  const float* h0 = (const float*)d_in[1];
  const float* c0 = (const float*)d_in[2];
  const float* W[4] = {(const float*)d_in[3], (const float*)d_in[6],
                       (const float*)d_in[9], (const float*)d_in[12]};
  const float* U[4] = {(const float*)d_in[4], (const float*)d_in[7],
                       (const float*)d_in[10], (const float*)d_in[13]};
  const float* bv[4] = {(const float*)d_in[5], (const float*)d_in[8],
                        (const float*)d_in[11], (const float*)d_in[14]};
  const float* Wd1 = (const float*)d_in[15];
  const float* bd1 = (const float*)d_in[16];
  const float* Wd2 = (const float*)d_in[17];
  const float* bd2 = (const float*)d_in[18];
  float* out = (float*)d_out;

  float* ws = (float*)d_ws;
  float* xWp = ws;                               // 16,777,216 f (64MB)
  short* Utp0 = (short*)(ws + 16777216);         // 4,194,304 bf16
  short* Utp1 = (short*)(ws + 18874368);         // 4,194,304 bf16
  short* Wt0 = (short*)(ws + 20971520);          // 4,194,304 bf16
  short* Wt1 = (short*)(ws + 23068672);          // 4,194,304 bf16
  short* xb = (short*)(ws + 25165824);           // 2,097,152 bf16
  short* hx = (short*)(ws + 26214400);           // 129*32768 bf16
  float* cst = ws + 28327936;                    // 32,768 f
  float* bp = ws + 28360704;                     // 16,384 f
  unsigned* arr = (unsigned*)(ws + 28377088);    // 4,096 u32 block flags
  short* D1 = (short*)xWp;  // alias: writes land after xWp rows consumed

  zero_cnt<<<16, 256, 0, stream>>>(arr);
  init2<<<128, 256, 0, stream>>>(h0, c0, hx, cst);
  cast_x<<<1024, 256, 0, stream>>>(x, xb);
  bias_perm<<<64, 256, 0, stream>>>(bv[0], bv[1], bv[2], bv[3], bp);

  // pre-loop prep: U0, W0 (temp in Wt1), W1 (for l=0's GEMM helpers)
  transpose_cast<true><<<dim3(128, 32), 256, 0, stream>>>(U[0], Utp0, 1024, 4096);
  transpose_cast<true><<<dim3(128, 16), 256, 0, stream>>>(W[0], Wt1, 512, 4096);
  transpose_cast<true><<<dim3(128, 32), 256, 0, stream>>>(W[1], Wt0, 1024, 4096);
  gemm_bf16<1, false><<<dim3(32, 32), 256, 0, stream>>>(xb, Wt1, bp, xWp, 4096,
                                                        4096, 512);

  // l=0: transpose U1->Utp1, W2->Wt1 ; gemm-helpers: xW1 = h0seq@W1t (Wt0)
  lstm_persist<<<256, 256, 0, stream>>>(xWp, Utp0, hx, cst, arr, 0,
                                        U[1], Utp1, 4096, 1, W[2], Wt1, 4096, 1,
                                        Wt0, bp + 4096, xWp, 5, 1);
  // l=1: transpose U2->Utp0, W3->Wt0 ; gemm-helpers: xW2 (Wt1)
  lstm_persist<<<256, 256, 0, stream>>>(xWp, Utp1, hx, cst, arr, 128,
                                        U[2], Utp0, 4096, 1, W[3], Wt0, 4096, 1,
                                        Wt1, bp + 8192, xWp, 5, 1);
  // l=2: transpose U3->Utp1, Wd1->Wt1 ; gemm-helpers: xW3 (Wt0)
  lstm_persist<<<256, 256, 0, stream>>>(xWp, Utp0, hx, cst, arr, 256,
                                        U[3], Utp1, 4096, 1, Wd1, Wt1, 1024, 0,
                                        Wt0, bp + 12288, xWp, 5, 1);
  // l=3: transpose Wd2->Utp0 ; gemm-helpers: D1 = relu(seq@Wd1t + bd1) (Wt1)
  lstm_persist<<<256, 256, 0, stream>>>(xWp, Utp1, hx, cst, arr, 384,
                                        Wd2, Utp0, 512, 0, nullptr, nullptr, 0,
                                        0, Wt1, bd1, D1, 3, 2);

  // final: out = D1 @ Wd2t + bd2  (B,T,E)
  gemm_bf16<3, false><<<dim3(4, 32), 256, 0, stream>>>(D1, Utp0, bd2, out, 4096,
                                                       512, 1024);
  finalize2<<<128, 256, 0, stream>>>(hx, cst, out + 2097152);
}

// Round 16
// 1890.467 us; speedup vs baseline: 1.0482x; 1.0482x over previous
//
#include <hip/hip_runtime.h>
#include <cmath>

// B=32, T=128, E=512, H=1024, 4H=4096
typedef __attribute__((ext_vector_type(8))) short short8;
typedef __attribute__((ext_vector_type(4))) float f32x4;
typedef unsigned long long u64;

__device__ inline short bf16r(float x) {
  union { float f; unsigned u; } v; v.f = x;
  unsigned r = (v.u + 0x7fff + ((v.u >> 16) & 1)) >> 16;
  return (short)r;
}
__device__ inline float bf2f(short s) {
  union { unsigned u; float f; } v; v.u = ((unsigned)(unsigned short)s) << 16;
  return v.f;
}

// hx layout: [t][chunk c=u>>4][b(32)][u&15] bf16 ; 129 buffers of 32768 shorts.
// ---------- small prep kernels ----------
__global__ __launch_bounds__(256) void init2(const float* __restrict__ h0,
                                             const float* __restrict__ c0,
                                             short* __restrict__ hx0,
                                             float* __restrict__ c) {
  int idx = blockIdx.x * 256 + threadIdx.x;  // (b,u) row-major
  int b = idx >> 10, u = idx & 1023;
  hx0[(u >> 4) * 512 + b * 16 + (u & 15)] = bf16r(h0[idx]);
  c[idx] = c0[idx];
}

__global__ __launch_bounds__(256) void finalize2(const short* __restrict__ hxf,
                                                 const float* __restrict__ c,
                                                 float* __restrict__ out) {
  int idx = blockIdx.x * 256 + threadIdx.x;  // (b,u)
  int b = idx >> 10, u = idx & 1023;
  out[idx] = bf2f(hxf[(u >> 4) * 512 + b * 16 + (u & 15)]);
  out[32768 + idx] = c[idx];
}

__global__ __launch_bounds__(256) void zero_cnt(unsigned* __restrict__ c) {
  c[blockIdx.x * 256 + threadIdx.x] = 0u;  // 16 blocks -> 4096 u32
}

// x (B,T,E) fp32 -> xb rows r=t*32+b, (4096,512) bf16 ; 8 elems/thread
__global__ __launch_bounds__(256) void cast_x(const float* __restrict__ x,
                                              short* __restrict__ xb) {
  int v = blockIdx.x * 256 + threadIdx.x;  // 0..262143 (vector index)
  int e8 = v & 63, t = (v >> 6) & 127, b = v >> 13;
  const float* src = x + (((size_t)b * 128 + t) << 9) + e8 * 8;
  float4 f0 = *(const float4*)src;
  float4 f1 = *(const float4*)(src + 4);
  short8 o;
  o[0] = bf16r(f0.x); o[1] = bf16r(f0.y); o[2] = bf16r(f0.z); o[3] = bf16r(f0.w);
  o[4] = bf16r(f1.x); o[5] = bf16r(f1.y); o[6] = bf16r(f1.z); o[7] = bf16r(f1.w);
  *(short8*)(xb + ((((t << 5) + b) << 9) + e8 * 8)) = o;
}

// permuted biases: bp[l][n'] = b_l[(n'&3)*1024 + (n'>>2)]
__global__ __launch_bounds__(256) void bias_perm(const float* __restrict__ b1,
                                                 const float* __restrict__ b2,
                                                 const float* __restrict__ b3,
                                                 const float* __restrict__ b4,
                                                 float* __restrict__ bp) {
  int idx = blockIdx.x * 256 + threadIdx.x;  // 0..16383
  int l = idx >> 12, c = idx & 4095;
  const float* s = (l == 0) ? b1 : (l == 1) ? b2 : (l == 2) ? b3 : b4;
  bp[idx] = s[((c & 3) << 10) | (c >> 2)];
}

// in fp32 (R,C) -> out bf16 (C,R); GPERM: out-row n' = (c&1023)*4 + (c>>10)
template <bool GPERM>
__global__ __launch_bounds__(256) void transpose_cast(const float* __restrict__ in,
                                                      short* __restrict__ out,
                                                      int R, int C) {
  __shared__ float tile[32][33];
  int c0 = blockIdx.x * 32, r0 = blockIdx.y * 32;
  int x = threadIdx.x & 31, y = threadIdx.x >> 5;
#pragma unroll
  for (int i = 0; i < 4; ++i)
    tile[y + i * 8][x] = in[(size_t)(r0 + y + i * 8) * C + c0 + x];
  __syncthreads();
#pragma unroll
  for (int i = 0; i < 4; ++i) {
    int c = c0 + y + i * 8;
    int n = GPERM ? (((c & 1023) << 2) | (c >> 10)) : c;
    out[(size_t)n * R + r0 + x] = bf16r(tile[x][y + i * 8]);
  }
}

// ---------- bf16 MFMA GEMM (standalone; used for layer-0 xW and final out) ----
template <int MODE, bool AHX>
__global__ __launch_bounds__(256) void gemm_bf16(const short* __restrict__ A,
                                                 const short* __restrict__ Bt,
                                                 const float* __restrict__ bias,
                                                 void* __restrict__ Cout,
                                                 int M, int N, int K) {
  __shared__ short As[128 * 40];
  __shared__ short Bs[128 * 40];
  const int tid = threadIdx.x;
  const int lane = tid & 63, wave = tid >> 6;
  const int lrow = lane & 15, lk = lane >> 4;
  const int m0 = (wave >> 1) * 64, n0 = (wave & 1) * 64;
  const int r = tid & 127, half = tid >> 7;
  const int mbase = blockIdx.y * 128, nbase = blockIdx.x * 128;

  f32x4 acc[4][4] = {};

  const short* Ab = A + (size_t)(mbase + r) * K + half * 16;
  const short* Ahx =
      A + (size_t)((mbase + r) >> 5) * 32768 + half * 512 + ((mbase + r) & 31) * 16;
  const short* Bb = Bt + (size_t)(nbase + r) * K + half * 16;
  short* AsW = As + r * 40 + half * 16;
  short* BsW = Bs + r * 40 + half * 16;

  for (int k0 = 0; k0 < K; k0 += 32) {
    short8 av0, av1;
    if constexpr (AHX) {
      const short* ap = Ahx + (k0 >> 4) * 512;
      av0 = *(const short8*)ap;
      av1 = *(const short8*)(ap + 8);
    } else {
      av0 = *(const short8*)(Ab + k0);
      av1 = *(const short8*)(Ab + k0 + 8);
    }
    short8 bv0 = *(const short8*)(Bb + k0);
    short8 bv1 = *(const short8*)(Bb + k0 + 8);
    __syncthreads();
    *(short8*)(AsW) = av0;
    *(short8*)(AsW + 8) = av1;
    *(short8*)(BsW) = bv0;
    *(short8*)(BsW + 8) = bv1;
    __syncthreads();
    short8 af[4], bfr[4];
#pragma unroll
    for (int i = 0; i < 4; ++i)
      af[i] = *(const short8*)(As + (m0 + i * 16 + lrow) * 40 + lk * 8);
#pragma unroll
    for (int i = 0; i < 4; ++i)
      bfr[i] = *(const short8*)(Bs + (n0 + i * 16 + lrow) * 40 + lk * 8);
#pragma unroll
    for (int i = 0; i < 4; ++i)
#pragma unroll
      for (int j = 0; j < 4; ++j)
        acc[i][j] = __builtin_amdgcn_mfma_f32_16x16x32_bf16(af[i], bfr[j],
                                                            acc[i][j], 0, 0, 0);
  }

#pragma unroll
  for (int i = 0; i < 4; ++i) {
    const int grow0 = mbase + m0 + i * 16 + lk * 4;
#pragma unroll
    for (int j = 0; j < 4; ++j) {
      const int gcol = nbase + n0 + j * 16 + lrow;
      const float bv = bias[gcol];
      f32x4 v = acc[i][j];
      if constexpr (MODE == 1) {
        float* o = (float*)Cout;
#pragma unroll
        for (int jj = 0; jj < 4; ++jj)
          o[(size_t)(grow0 + jj) * N + gcol] = v[jj] + bv;
      } else if constexpr (MODE == 2) {
        short* o = (short*)Cout;
#pragma unroll
        for (int jj = 0; jj < 4; ++jj)
          o[(size_t)(grow0 + jj) * N + gcol] = bf16r(fmaxf(v[jj] + bv, 0.f));
      } else {
        float* o = (float*)Cout;
#pragma unroll
        for (int jj = 0; jj < 4; ++jj) {
          int rr = grow0 + jj;
          int orow = ((rr & 31) << 7) | (rr >> 5);
          o[(size_t)orow * N + gcol] = v[jj] + bv;
        }
      }
    }
  }
}

// ---------- persistent recurrent kernel (whole layer, 128 steps) ----------
// Grid = 256 blocks (1 block/CU). Blocks 0..63: recurrence (R8 protocol with
// SINGLE-PHASE poll — wave 0's 64 lanes poll all 64 flags in parallel — and
// direct per-lane 2B h-stores, no shfl pack; 2 barriers/step). Blocks
// 64..127: transpose helpers. Blocks 128..255: GEMM helpers (next layer's
// xW / dense D1), tile-gated on producer flags with long-sleep polling.
#define PBLK 64
__global__ __launch_bounds__(256) void lstm_persist(
    const float* xWp, const short* __restrict__ Utp, short* __restrict__ hx,
    float* __restrict__ cst, unsigned* __restrict__ arr, int ebase,
    const float* __restrict__ tA, short* __restrict__ oA, int CA, int gpA,
    const float* __restrict__ tB, short* __restrict__ oB, int CB, int gpB,
    const short* __restrict__ gBt, const float* __restrict__ gBias, void* gOut,
    int gLg, int gMode) {
  __shared__ short Hs[32768];  // 64KB: h_t chunks (compute) / As+Bs (gemm help)
  __shared__ float tile[32][33];
  const int tid = threadIdx.x;
  const int bid = blockIdx.x;

  if (bid >= 128) {  // ---- GEMM helper: next layer's xW (or dense D1) ----
    const int hid = bid - 128;  // 0..127
    const int lane = tid & 63, wave = tid >> 6;
    const int lrow = lane & 15, lk = lane >> 4;
    const int m0 = (wave >> 1) * 64, n0 = (wave & 1) * 64;
    const int r = tid & 127, half = tid >> 7;
    const short* hxseq = hx + 32768;
    short* As = Hs;
    short* Bs = Hs + 5120;
    const int ntiles = 32 << gLg;
    int lastby = -1;
    for (int ti = hid; ti < ntiles; ti += 128) {
      const int by = ti >> gLg, bx = ti - (by << gLg);
      if (by != lastby) {
        lastby = by;
        const unsigned tgt = (unsigned)(ebase + 4 * by + 4);
        if (tid < PBLK)
          while (__hip_atomic_load(arr + (tid << 6), __ATOMIC_RELAXED,
                                   __HIP_MEMORY_SCOPE_AGENT) < tgt)
            __builtin_amdgcn_s_sleep(32);  // helpers have ~14us slack: poll
                                           // rarely, don't contend flag lines
        __syncthreads();
      }
      const int mbase = by * 128, nbase = bx * 128;
      f32x4 acc[4][4] = {};
      const short* Ahx = hxseq + (size_t)((mbase + r) >> 5) * 32768 +
                         half * 512 + ((mbase + r) & 31) * 16;
      const short* Bb = gBt + (size_t)(nbase + r) * 1024 + half * 16;
      short* AsW = As + r * 40 + half * 16;
      short* BsW = Bs + r * 40 + half * 16;
      for (int k0 = 0; k0 < 1024; k0 += 32) {
        const short* ap = Ahx + (k0 >> 4) * 512;
        short8 av0 = *(const short8*)ap;
        short8 av1 = *(const short8*)(ap + 8);
        short8 bv0 = *(const short8*)(Bb + k0);
        short8 bv1 = *(const short8*)(Bb + k0 + 8);
        __syncthreads();
        *(short8*)(AsW) = av0;
        *(short8*)(AsW + 8) = av1;
        *(short8*)(BsW) = bv0;
        *(short8*)(BsW + 8) = bv1;
        __syncthreads();
        short8 af[4], bfr[4];
#pragma unroll
        for (int i = 0; i < 4; ++i)
          af[i] = *(const short8*)(As + (m0 + i * 16 + lrow) * 40 + lk * 8);
#pragma unroll
        for (int i = 0; i < 4; ++i)
          bfr[i] = *(const short8*)(Bs + (n0 + i * 16 + lrow) * 40 + lk * 8);
#pragma unroll
        for (int i = 0; i < 4; ++i)
#pragma unroll
          for (int j = 0; j < 4; ++j)
            acc[i][j] = __builtin_amdgcn_mfma_f32_16x16x32_bf16(
                af[i], bfr[j], acc[i][j], 0, 0, 0);
      }
#pragma unroll
      for (int i = 0; i < 4; ++i) {
        const int grow0 = mbase + m0 + i * 16 + lk * 4;
#pragma unroll
        for (int j = 0; j < 4; ++j) {
          const int gcol = nbase + n0 + j * 16 + lrow;
          const float bv = gBias[gcol];
          f32x4 v = acc[i][j];
          if (gMode == 1) {
            float* o = (float*)gOut;
#pragma unroll
            for (int jj = 0; jj < 4; ++jj)
              o[(size_t)(grow0 + jj) * 4096 + gcol] = v[jj] + bv;
          } else {
            short* o = (short*)gOut;
#pragma unroll
            for (int jj = 0; jj < 4; ++jj)
              o[(size_t)(grow0 + jj) * 1024 + gcol] =
                  bf16r(fmaxf(v[jj] + bv, 0.f));
          }
        }
      }
      __syncthreads();  // WAR before next tile's staging writes
    }
    return;
  }

  if (bid >= PBLK) {  // ---- transpose helper: next stage's weights ----
    const int hid = bid - PBLK;
    const int x = tid & 31, y = tid >> 5;
    for (int job = 0; job < 2; ++job) {
      const float* in = job ? tB : tA;
      short* out = job ? oB : oA;
      const int C = job ? CB : CA;
      const int gp = job ? gpB : gpA;
      const int ctiles = C >> 5;
      for (int ti = hid; ti < C; ti += 64) {
        const int cx = ti % ctiles, ry = ti / ctiles;
        __syncthreads();
#pragma unroll
        for (int i = 0; i < 4; ++i)
          tile[y + i * 8][x] = in[(size_t)(ry * 32 + y + i * 8) * C + cx * 32 + x];
        __syncthreads();
#pragma unroll
        for (int i = 0; i < 4; ++i) {
          int c = cx * 32 + y + i * 8;
          int n = gp ? (((c & 1023) << 2) | (c >> 10)) : c;
          out[(size_t)n * 1024 + ry * 32 + x] = bf16r(tile[x][y + i * 8]);
        }
      }
    }
    return;
  }

  // ---- recurrence block (R8 protocol, single-phase poll, direct stores) ----
  const int lane = tid & 63, wave = tid >> 6;
  const int lrow = lane & 15, lk = lane >> 4;
  const int ucol = bid * 64 + wave * 16 + lrow;    // A-operand row (U col)
  const int col4 = bid * 64 + wave * 16 + lk * 4;  // first z-col of this lane
  const int u = bid * 16 + wave * 4 + lk;          // unit owned by this lane

  short8 ureg[32];
  {
    const short* Ub = Utp + (size_t)ucol * 1024 + lk * 8;
#pragma unroll
    for (int j = 0; j < 32; ++j) ureg[j] = *(const short8*)(Ub + j * 32);
  }

  float creg0 = cst[lrow * 1024 + u];
  float creg1 = cst[(lrow + 16) * 1024 + u];

  f32x4 cur0 = *(const f32x4*)(xWp + (size_t)lrow * 4096 + col4);
  f32x4 cur1 = *(const f32x4*)(xWp + (size_t)(lrow + 16) * 4096 + col4);

  // per-lane direct h-store offset (shorts): chunk bid, b=lrow(/lrow+16),
  // u&15 = wave*4+lk  ->  bid*512 + b*16 + wave*4 + lk
  const int hoff = bid * 512 + lrow * 16 + wave * 4 + lk;

  for (int t = 0; t < 128; ++t) {
    const unsigned ep = (unsigned)(ebase + t);
    const char* src = (const char*)(hx + (size_t)t * 32768) + tid * 16;
    char* dst = (char*)Hs + tid * 16;

    if (t) {
      // single-phase poll: wave 0's 64 lanes cover all 64 flags in parallel
      if (tid < 64)
        while (__hip_atomic_load(arr + (tid << 6), __ATOMIC_RELAXED,
                                 __HIP_MEMORY_SCOPE_AGENT) < ep)
          __builtin_amdgcn_s_sleep(1);
      __syncthreads();  // flags seen + WAR on Hs (prev step's reads done)
    }
#pragma unroll
    for (int i = 0; i < 16; ++i)
      __builtin_amdgcn_global_load_lds(
          (const __attribute__((address_space(1))) void*)(src + i * 4096),
          (__attribute__((address_space(3))) void*)(dst + i * 4096), 16, 0, 0);
    __syncthreads();  // staging complete

    f32x4 acc0 = cur0, acc1 = cur1;

    // prefetch next step's xW (completes during MFMA/gates)
    if (t < 127) {
      const float* xb = xWp + (size_t)(t + 1) * 32 * 4096 + col4;
      cur0 = *(const f32x4*)(xb + (size_t)lrow * 4096);
      cur1 = *(const f32x4*)(xb + (size_t)(lrow + 16) * 4096);
    }

    // MFMA (swapped): acc = U-frag x h-frag
    const char* HsB = (const char*)Hs;
#pragma unroll
    for (int j = 0; j < 32; ++j) {
      int c0 = (2 * j + (lk >> 1)) * 1024 + lrow * 32 + (lk & 1) * 16;
      short8 b0 = *(const short8*)(HsB + c0);
      short8 b1 = *(const short8*)(HsB + c0 + 512);
      acc0 = __builtin_amdgcn_mfma_f32_16x16x32_bf16(ureg[j], b0, acc0, 0, 0, 0);
      acc1 = __builtin_amdgcn_mfma_f32_16x16x32_bf16(ureg[j], b1, acc1, 0, 0, 0);
    }

    // gates: all 4 in-lane (gate = reg index)
    unsigned short p0, p1;
    {
      float gi = 1.f / (1.f + __expf(-acc0[0]));
      float gf = 1.f / (1.f + __expf(-acc0[1]));
      float gg = fmaxf(acc0[2], 0.f);
      float go = 1.f / (1.f + __expf(-acc0[3]));
      float cn = gf * creg0 + gi * gg;
      creg0 = cn;
      p0 = (unsigned short)bf16r(go * fmaxf(cn, 0.f));
    }
    {
      float gi = 1.f / (1.f + __expf(-acc1[0]));
      float gf = 1.f / (1.f + __expf(-acc1[1]));
      float gg = fmaxf(acc1[2], 0.f);
      float go = 1.f / (1.f + __expf(-acc1[3]));
      float cn = gf * creg1 + gi * gg;
      creg1 = cn;
      p1 = (unsigned short)bf16r(go * fmaxf(cn, 0.f));
    }

    // direct per-lane 2B stores (same bytes as the old shfl-pack u64 path)
    {
      unsigned short* hnx =
          (unsigned short*)(hx + (size_t)(t + 1) * 32768 + hoff);
      __hip_atomic_store(hnx, p0, __ATOMIC_RELAXED, __HIP_MEMORY_SCOPE_AGENT);
      __hip_atomic_store(hnx + 256, p1, __ATOMIC_RELAXED,
                         __HIP_MEMORY_SCOPE_AGENT);  // (lrow+16)*16 - lrow*16
      if (t == 127) {  // final h -> hx[0] (replaces copy_h; same values)
        unsigned short* hz = (unsigned short*)(hx + hoff);
        __hip_atomic_store(hz, p0, __ATOMIC_RELAXED, __HIP_MEMORY_SCOPE_AGENT);
        __hip_atomic_store(hz + 256, p1, __ATOMIC_RELAXED,
                           __HIP_MEMORY_SCOPE_AGENT);
      }
    }

    // drain + flag EVERY step (incl. t==127 so helpers can gate on h[127])
    __syncthreads();
    if (tid == 0)
      __hip_atomic_store(arr + (bid << 6), (unsigned)(ebase + t + 1),
                         __ATOMIC_RELAXED, __HIP_MEMORY_SCOPE_AGENT);
  }

  cst[lrow * 1024 + u] = creg0;
  cst[(lrow + 16) * 1024 + u] = creg1;
}

// ---------- launch ----------
extern "C" void kernel_launch(void* const* d_in, const int* in_sizes, int n_in,
                              void* d_out, int out_size, void* d_ws, size_t ws_size,
                              hipStream_t stream) {
  const float* x = (const float*)d_in[0];
  const float* h0 = (const float*)d_in[1];
  const float* c0 = (const float*)d_in[2];
  const float* W[4] = {(const float*)d_in[3], (const float*)d_in[6],
                       (const float*)d_in[9], (const float*)d_in[12]};
  const float* U[4] = {(const float*)d_in[4], (const float*)d_in[7],
                       (const float*)d_in[10], (const float*)d_in[13]};
  const float* bv[4] = {(const float*)d_in[5], (const float*)d_in[8],
                        (const float*)d_in[11], (const float*)d_in[14]};
  const float* Wd1 = (const float*)d_in[15];
  const float* bd1 = (const float*)d_in[16];
  const float* Wd2 = (const float*)d_in[17];
  const float* bd2 = (const float*)d_in[18];
  float* out = (float*)d_out;

  float* ws = (float*)d_ws;
  float* xWp = ws;                               // 16,777,216 f (64MB)
  short* Utp0 = (short*)(ws + 16777216);         // 4,194,304 bf16
  short* Utp1 = (short*)(ws + 18874368);         // 4,194,304 bf16
  short* Wt0 = (short*)(ws + 20971520);          // 4,194,304 bf16
  short* Wt1 = (short*)(ws + 23068672);          // 4,194,304 bf16
  short* xb = (short*)(ws + 25165824);           // 2,097,152 bf16
  short* hx = (short*)(ws + 26214400);           // 129*32768 bf16
  float* cst = ws + 28327936;                    // 32,768 f
  float* bp = ws + 28360704;                     // 16,384 f
  unsigned* arr = (unsigned*)(ws + 28377088);    // 4,096 u32 block flags
  short* D1 = (short*)xWp;  // alias: writes land after xWp rows consumed

  zero_cnt<<<16, 256, 0, stream>>>(arr);
  init2<<<128, 256, 0, stream>>>(h0, c0, hx, cst);
  cast_x<<<1024, 256, 0, stream>>>(x, xb);
  bias_perm<<<64, 256, 0, stream>>>(bv[0], bv[1], bv[2], bv[3], bp);

  // pre-loop prep: U0, W0 (temp in Wt1), W1 (for l=0's GEMM helpers)
  transpose_cast<true><<<dim3(128, 32), 256, 0, stream>>>(U[0], Utp0, 1024, 4096);
  transpose_cast<true><<<dim3(128, 16), 256, 0, stream>>>(W[0], Wt1, 512, 4096);
  transpose_cast<true><<<dim3(128, 32), 256, 0, stream>>>(W[1], Wt0, 1024, 4096);
  gemm_bf16<1, false><<<dim3(32, 32), 256, 0, stream>>>(xb, Wt1, bp, xWp, 4096,
                                                        4096, 512);

  // l=0: transpose U1->Utp1, W2->Wt1 ; gemm-helpers: xW1 = h0seq@W1t (Wt0)
  lstm_persist<<<256, 256, 0, stream>>>(xWp, Utp0, hx, cst, arr, 0,
                                        U[1], Utp1, 4096, 1, W[2], Wt1, 4096, 1,
                                        Wt0, bp + 4096, xWp, 5, 1);
  // l=1: transpose U2->Utp0, W3->Wt0 ; gemm-helpers: xW2 (Wt1)
  lstm_persist<<<256, 256, 0, stream>>>(xWp, Utp1, hx, cst, arr, 128,
                                        U[2], Utp0, 4096, 1, W[3], Wt0, 4096, 1,
                                        Wt1, bp + 8192, xWp, 5, 1);
  // l=2: transpose U3->Utp1, Wd1->Wt1 ; gemm-helpers: xW3 (Wt0)
  lstm_persist<<<256, 256, 0, stream>>>(xWp, Utp0, hx, cst, arr, 256,
                                        U[3], Utp1, 4096, 1, Wd1, Wt1, 1024, 0,
                                        Wt0, bp + 12288, xWp, 5, 1);
  // l=3: transpose Wd2->Utp0 ; gemm-helpers: D1 = relu(seq@Wd1t + bd1) (Wt1)
  lstm_persist<<<256, 256, 0, stream>>>(xWp, Utp1, hx, cst, arr, 384,
                                        Wd2, Utp0, 512, 0, nullptr, nullptr, 0,
                                        0, Wt1, bd1, D1, 3, 2);

  // final: out = D1 @ Wd2t + bd2  (B,T,E)
  gemm_bf16<3, false><<<dim3(4, 32), 256, 0, stream>>>(D1, Utp0, bd2, out, 4096,
                                                       512, 1024);
  finalize2<<<128, 256, 0, stream>>>(hx, cst, out + 2097152);
}